// Round 5
// baseline (15502.594 us; speedup 1.0000x reference)
//
#include <hip/hip_runtime.h>
#include <hip/hip_bf16.h>

#define T_ 512
#define B_ 64
#define I_ 128
#define H_ 256
#define G_ 768   // 3H
#define L_ 6
#define M_ (T_ * B_)   // 32768

typedef __attribute__((ext_vector_type(8))) short short8;
typedef __attribute__((ext_vector_type(4))) float f32x4;
typedef __attribute__((ext_vector_type(4))) unsigned short us4;

__device__ __forceinline__ ushort f2bf(float x) {
    union { float f; unsigned u; } v; v.f = x;
    unsigned r = v.u + 0x7FFFu + ((v.u >> 16) & 1u);
    return (ushort)(r >> 16);
}
__device__ __forceinline__ float bf2f(ushort h) {
    union { unsigned u; float f; } v; v.u = ((unsigned)h) << 16;
    return v.f;
}
__device__ __forceinline__ float fast_rcp(float x) {
#if __has_builtin(__builtin_amdgcn_rcpf)
    return __builtin_amdgcn_rcpf(x);
#else
    return 1.0f / x;
#endif
}
// barrier without vmcnt(0) drain: LDS-visible only; global stores float across steps
__device__ __forceinline__ void wg_barrier() {
    asm volatile("s_waitcnt lgkmcnt(0)" ::: "memory");
    __builtin_amdgcn_s_barrier();
    asm volatile("" ::: "memory");
}

// dst[m][k] = bf16( src[m][ (k%768)*cols + k/768 ] ) -- the _eff reinterpretation
__global__ void k_transpose_cast(const float* __restrict__ src, ushort* __restrict__ dst,
                                 int cols) {
    long per = 768L * cols;
    long m = blockIdx.z;
    for (long k = (long)blockIdx.x * blockDim.x + threadIdx.x; k < per;
         k += (long)gridDim.x * blockDim.x) {
        long r = k % 768, c = k / 768;
        dst[m * per + k] = f2bf(src[m * per + r * cols + c]);
    }
}

__global__ void k_cast(const float* __restrict__ src, ushort* __restrict__ dst, long n) {
    long i = (long)blockIdx.x * blockDim.x + threadIdx.x;
    long stride = (long)gridDim.x * blockDim.x;
    for (; i < n; i += stride) dst[i] = f2bf(src[i]);
}

// gi layout per dir: [t][bt(4)][wv(16)][gate(3)][r16(16)][b(16)] bf16
// (bt = batch tile of 16; wv = 16-col slice owner wave; b = batch within tile)
// Scan thread (wv, r16, q) reads its 3 gate values at one pointer + {0,512,1024}B.
__global__ __launch_bounds__(256)
void k_gi_gemm(const ushort* __restrict__ A,    // [M][K] bf16
               const ushort* __restrict__ E,    // [2][768][K] bf16
               const float* __restrict__ bih,   // [2][768]
               const float* __restrict__ bhh,   // [2][768]
               ushort* __restrict__ gi,
               int K) {
    int dir = blockIdx.z;
    const ushort* Bd = E + (long)dir * G_ * K;
    const float* bi = bih + dir * G_;
    const float* bh = bhh + dir * G_;
    ushort* gid = gi + (long)dir * T_ * G_ * B_;

    int t = blockIdx.x;
    int n0 = blockIdx.y * 64;
    int lane = threadIdx.x & 63, w = threadIdx.x >> 6;
    int r16 = lane & 15, q = lane >> 4, koff = q * 8;

    const ushort* Arow = A + (long)(t * 64 + w * 16 + r16) * K + koff;
    const ushort* Brow[4];
#pragma unroll
    for (int nt = 0; nt < 4; nt++)
        Brow[nt] = Bd + (long)(n0 + nt * 16 + r16) * K + koff;

    f32x4 acc[4] = {{0.f,0.f,0.f,0.f},{0.f,0.f,0.f,0.f},{0.f,0.f,0.f,0.f},{0.f,0.f,0.f,0.f}};

    short8 a = *(const short8*)Arow;
    short8 b[4];
#pragma unroll
    for (int nt = 0; nt < 4; nt++) b[nt] = *(const short8*)Brow[nt];

    for (int k0 = 0; k0 < K; k0 += 32) {
        int kn = (k0 + 32 < K) ? (k0 + 32) : 0;
        short8 an = *(const short8*)(Arow + kn);
        short8 bn[4];
#pragma unroll
        for (int nt = 0; nt < 4; nt++) bn[nt] = *(const short8*)(Brow[nt] + kn);
#pragma unroll
        for (int nt = 0; nt < 4; nt++)
            acc[nt] = __builtin_amdgcn_mfma_f32_16x16x32_bf16(a, b[nt], acc[nt], 0, 0, 0);
        a = an;
#pragma unroll
        for (int nt = 0; nt < 4; nt++) b[nt] = bn[nt];
    }

    // GEMM wave w covers batch rows w*16..w*16+15 => bt == w
#pragma unroll
    for (int nt = 0; nt < 4; nt++) {
        int col = n0 + nt * 16 + r16;
        float bias = bi[col] + (col < 2 * H_ ? bh[col] : 0.f);
        us4 pk;
#pragma unroll
        for (int j = 0; j < 4; j++) pk[j] = f2bf(acc[nt][j] + bias);
        int gate = col >> 8, c = col & 255;
        int wv = c >> 4, r = c & 15;
        long idx = ((((long)t * 4 + w) * 16 + wv) * 3 + gate) * 256 + r * 16 + q * 4;
        *(us4*)(gid + idx) = pk;
    }
}

// Batch-split scan: 8 WGs (dir = bx>>2, btile = bx&3), 1024 thr = 16 waves.
// Wave wv owns h-cols [wv*16, wv*16+16) for ALL 3 gates -> bfrag = 96 VGPRs,
// total demand ~128 (4 waves/SIMD tier) -> genuinely register-resident.
template<int IS_LAST>
__global__ __launch_bounds__(1024, 4)
void k_scan(const ushort* __restrict__ gi,
            const ushort* __restrict__ Ehh,  // [2][768][256] bf16 (this layer)
            const float* __restrict__ bhh,   // [2][768]
            const float* __restrict__ h0,    // [2][64][256] f32 (this layer)
            ushort* __restrict__ out_bf,     // Xbuf [M][512] (layers 0..4)
            float* __restrict__ out_f) {     // d_out [M][512] (layer 5)
    int bx = blockIdx.x;
    int dir = bx >> 2, bt = bx & 3, b0 = bt * 16;
    int tid = threadIdx.x, lane = tid & 63, wv = tid >> 6;
    int r16 = lane & 15, q = lane >> 4;
    int js = wv * 16;

    const ushort* gid = gi + (long)dir * T_ * G_ * B_;
    const ushort* Ed  = Ehh + (long)dir * G_ * H_;
    const float*  bhd = bhh + dir * G_;
    const float*  h0d = h0 + (long)dir * B_ * H_;

    __shared__ ushort hl[2][16 * 256];   // 16 KiB, XOR-swizzled 512B rows

    // Whh fragments: 3 gates x 8 k-steps for this wave's 16 cols = 96 VGPRs
    short8 bfrag[3][8];
#pragma unroll
    for (int nt = 0; nt < 3; nt++) {
        int g = nt * H_ + js + r16;
#pragma unroll
        for (int ks = 0; ks < 8; ks++)
            bfrag[nt][ks] = *(const short8*)(Ed + (long)g * H_ + ks * 32 + q * 8);
    }
    float bhn = bhd[2 * H_ + js + r16];

    // init LDS h[0] (swizzled): wave wv loads batch row wv; lane covers 4 cols
    {
        int row = wv, c0 = lane * 4;
        const float* src = h0d + (long)(b0 + row) * H_ + c0;
        us4 pk;
#pragma unroll
        for (int i = 0; i < 4; i++) pk[i] = f2bf(src[i]);
        char* dst = (char*)&hl[0][0] + row * 512 + ((c0 * 2) ^ ((row & 7) << 4));
        *(us4*)dst = pk;
    }
    // h_old carried per-lane as packed bf16 (rows q*4+j, col js+r16)
    us4 hprev;
#pragma unroll
    for (int j = 0; j < 4; j++)
        hprev[j] = f2bf(h0d[(long)(b0 + q * 4 + j) * H_ + js + r16]);
    wg_barrier();

    int t0 = dir ? (T_ - 1) : 0;
    long gstep = dir ? -(long)(4 * 16 * 3 * 256) : (long)(4 * 16 * 3 * 256);
    const ushort* gp = gid + ((((long)t0 * 4 + bt) * 16 + wv) * 3) * 256 + r16 * 16 + q * 4;

    // output bounce: row = wv, lane covers 8B (4 bf16) of the 512B row chunk
    int brow = wv;
    long xstep = dir ? -(long)B_ * 512 : (long)B_ * 512;
    ushort* xp = out_bf + ((long)t0 * B_ + b0 + brow) * 512 + dir * H_ + lane * 4;
    float*  fp = out_f  + ((long)t0 * B_ + b0 + brow) * 512 + dir * H_ + lane * 4;
    int bnc_off = brow * 512 + ((lane * 8) ^ ((brow & 7) << 4));

    int sw = (r16 & 7) << 4;
    for (int s = 0; s < T_; s++) {
        const char* hc = (const char*)&hl[s & 1][0];
        char* hn_ = (char*)&hl[(s & 1) ^ 1][0];

        // gi loads for this step (3 x 8B at one pointer + imm offsets), issued early
        us4 gv0 = *(const us4*)(gp);
        us4 gv1 = *(const us4*)(gp + 256);
        us4 gv2 = *(const us4*)(gp + 512);
        gp += gstep;

        // bounce previous step's h (in hc) to global, coalesced
        if (s) {
            us4 v = *(const us4*)(hc + bnc_off);
            if (IS_LAST) {
                f32x4 f0;
#pragma unroll
                for (int i = 0; i < 4; i++) f0[i] = bf2f(v[i]);
                *(f32x4*)fp = f0;
                fp += xstep;
            } else {
                *(us4*)xp = v;
                xp += xstep;
            }
        }

        // gh = h @ Whh^T for this wave's 16 cols, 3 gates
        f32x4 acc0 = {0.f, 0.f, 0.f, 0.f};
        f32x4 acc1 = {0.f, 0.f, 0.f, 0.f};
        f32x4 acc2 = {bhn, bhn, bhn, bhn};
#pragma unroll
        for (int ks = 0; ks < 8; ks++) {
            short8 a = *(const short8*)(hc + r16 * 512 + ((ks * 64 + q * 16) ^ sw));
            acc0 = __builtin_amdgcn_mfma_f32_16x16x32_bf16(a, bfrag[0][ks], acc0, 0, 0, 0);
            acc1 = __builtin_amdgcn_mfma_f32_16x16x32_bf16(a, bfrag[1][ks], acc1, 0, 0, 0);
            acc2 = __builtin_amdgcn_mfma_f32_16x16x32_bf16(a, bfrag[2][ks], acc2, 0, 0, 0);
        }

        // gates + state update; h_new -> other LDS buffer (swizzled)
        int col = js + r16;
#pragma unroll
        for (int j = 0; j < 4; j++) {
            int row = q * 4 + j;
            float xr = acc0[j] + bf2f(gv0[j]);
            float xz = acc1[j] + bf2f(gv1[j]);
            float r = fast_rcp(1.f + __expf(-xr));
            float z = fast_rcp(1.f + __expf(-xz));
            float xn = bf2f(gv2[j]) + r * acc2[j];
            float n = 1.f - 2.f * fast_rcp(__expf(2.f * xn) + 1.f);  // tanh
            float hnew = n + z * (bf2f(hprev[j]) - n);
            ushort us = f2bf(hnew);
            hprev[j] = us;
            *(ushort*)(hn_ + row * 512 + ((col * 2) ^ ((row & 7) << 4))) = us;
        }
        wg_barrier();
    }

    // final bounce: h(T-1) sits in hl[0]
    {
        const char* hc = (const char*)&hl[0][0];
        us4 v = *(const us4*)(hc + bnc_off);
        if (IS_LAST) {
            f32x4 f0;
#pragma unroll
            for (int i = 0; i < 4; i++) f0[i] = bf2f(v[i]);
            *(f32x4*)fp = f0;
        } else {
            *(us4*)xp = v;
        }
    }
}

extern "C" void kernel_launch(void* const* d_in, const int* in_sizes, int n_in,
                              void* d_out, int out_size, void* d_ws, size_t ws_size,
                              hipStream_t stream) {
    const float* x      = (const float*)d_in[0];
    const float* h0     = (const float*)d_in[1];
    const float* w_ih_0 = (const float*)d_in[2];
    const float* w_hh_0 = (const float*)d_in[3];
    const float* b_ih_0 = (const float*)d_in[4];
    const float* b_hh_0 = (const float*)d_in[5];
    const float* w_ih_r = (const float*)d_in[6];
    const float* w_hh_r = (const float*)d_in[7];
    const float* b_ih_r = (const float*)d_in[8];
    const float* b_hh_r = (const float*)d_in[9];
    float* out = (float*)d_out;

    char* ws = (char*)d_ws;
    size_t off = 0;
    auto alloc = [&](size_t bytes) -> void* {
        void* p = ws + off;
        off = (off + bytes + 255) & ~(size_t)255;
        return p;
    };
    ushort* Ehh  = (ushort*)alloc(12L * G_ * H_ * 2);        // [6][2][768][256]
    ushort* Eih0 = (ushort*)alloc(2L * G_ * I_ * 2);         // [2][768][128]
    ushort* EihR = (ushort*)alloc(10L * G_ * 512 * 2);       // [5][2][768][512]
    ushort* gi   = (ushort*)alloc(2L * T_ * G_ * B_ * 2);    // [2][512][4][16][3][256] (tiled)
    ushort* Xbuf = (ushort*)alloc((long)M_ * 512 * 2);       // [32768][512]

    k_transpose_cast<<<dim3(256, 1, 2),  256, 0, stream>>>(w_hh_0, Ehh, H_);
    k_transpose_cast<<<dim3(256, 1, 10), 256, 0, stream>>>(w_hh_r, Ehh + 2L * G_ * H_, H_);
    k_transpose_cast<<<dim3(128, 1, 2),  256, 0, stream>>>(w_ih_0, Eih0, I_);
    k_transpose_cast<<<dim3(512, 1, 10), 256, 0, stream>>>(w_ih_r, EihR, 512);
    k_cast<<<dim3(2048), 256, 0, stream>>>(x, Xbuf, (long)M_ * I_);

    for (int l = 0; l < L_; l++) {
        int K = (l == 0) ? I_ : 512;
        const ushort* Eih = (l == 0) ? Eih0 : (EihR + (long)(l - 1) * 2 * G_ * 512);
        const float* bih = (l == 0) ? b_ih_0 : (b_ih_r + (long)(l - 1) * 2 * G_);
        const float* bhh = (l == 0) ? b_hh_0 : (b_hh_r + (long)(l - 1) * 2 * G_);
        const ushort* Ehl = Ehh + (long)l * 2 * G_ * H_;
        const float* h0l = h0 + (long)l * 2 * B_ * H_;

        k_gi_gemm<<<dim3(T_, G_ / 64, 2), 256, 0, stream>>>(Xbuf, Eih, bih, bhh, gi, K);

        if (l == L_ - 1)
            k_scan<1><<<dim3(8), dim3(1024), 0, stream>>>(gi, Ehl, bhh, h0l, Xbuf, out);
        else
            k_scan<0><<<dim3(8), dim3(1024), 0, stream>>>(gi, Ehl, bhh, h0l, Xbuf, out);
    }
}

// Round 6
// 15423.924 us; speedup vs baseline: 1.0051x; 1.0051x over previous
//
#include <hip/hip_runtime.h>
#include <hip/hip_bf16.h>

#define T_ 512
#define B_ 64
#define I_ 128
#define H_ 256
#define G_ 768   // 3H
#define L_ 6
#define M_ (T_ * B_)   // 32768

typedef __attribute__((ext_vector_type(8))) short short8;
typedef __attribute__((ext_vector_type(4))) float f32x4;
typedef __attribute__((ext_vector_type(4))) unsigned short us4;

__device__ __forceinline__ ushort f2bf(float x) {
    union { float f; unsigned u; } v; v.f = x;
    unsigned r = v.u + 0x7FFFu + ((v.u >> 16) & 1u);
    return (ushort)(r >> 16);
}
__device__ __forceinline__ float bf2f(ushort h) {
    union { unsigned u; float f; } v; v.u = ((unsigned)h) << 16;
    return v.f;
}
__device__ __forceinline__ float fast_rcp(float x) {
#if __has_builtin(__builtin_amdgcn_rcpf)
    return __builtin_amdgcn_rcpf(x);
#else
    return 1.0f / x;
#endif
}
// barrier without vmcnt(0) drain: LDS-visible only; global stores float across steps
__device__ __forceinline__ void wg_barrier() {
    asm volatile("s_waitcnt lgkmcnt(0)" ::: "memory");
    __builtin_amdgcn_s_barrier();
    asm volatile("" ::: "memory");
}

// dst[m][k] = bf16( src[m][ (k%768)*cols + k/768 ] ) -- the _eff reinterpretation
__global__ void k_transpose_cast(const float* __restrict__ src, ushort* __restrict__ dst,
                                 int cols) {
    long per = 768L * cols;
    long m = blockIdx.z;
    for (long k = (long)blockIdx.x * blockDim.x + threadIdx.x; k < per;
         k += (long)gridDim.x * blockDim.x) {
        long r = k % 768, c = k / 768;
        dst[m * per + k] = f2bf(src[m * per + r * cols + c]);
    }
}

__global__ void k_cast(const float* __restrict__ src, ushort* __restrict__ dst, long n) {
    long i = (long)blockIdx.x * blockDim.x + threadIdx.x;
    long stride = (long)gridDim.x * blockDim.x;
    for (; i < n; i += stride) dst[i] = f2bf(src[i]);
}

// gi layout per dir: [t][bt(4)][wv(16)][gate(3)][r16(16)][b(16)] bf16
__global__ __launch_bounds__(256)
void k_gi_gemm(const ushort* __restrict__ A,    // [M][K] bf16
               const ushort* __restrict__ E,    // [2][768][K] bf16
               const float* __restrict__ bih,   // [2][768]
               const float* __restrict__ bhh,   // [2][768]
               ushort* __restrict__ gi,
               int K) {
    int dir = blockIdx.z;
    const ushort* Bd = E + (long)dir * G_ * K;
    const float* bi = bih + dir * G_;
    const float* bh = bhh + dir * G_;
    ushort* gid = gi + (long)dir * T_ * G_ * B_;

    int t = blockIdx.x;
    int n0 = blockIdx.y * 64;
    int lane = threadIdx.x & 63, w = threadIdx.x >> 6;
    int r16 = lane & 15, q = lane >> 4, koff = q * 8;

    const ushort* Arow = A + (long)(t * 64 + w * 16 + r16) * K + koff;
    const ushort* Brow[4];
#pragma unroll
    for (int nt = 0; nt < 4; nt++)
        Brow[nt] = Bd + (long)(n0 + nt * 16 + r16) * K + koff;

    f32x4 acc[4] = {{0.f,0.f,0.f,0.f},{0.f,0.f,0.f,0.f},{0.f,0.f,0.f,0.f},{0.f,0.f,0.f,0.f}};

    short8 a = *(const short8*)Arow;
    short8 b[4];
#pragma unroll
    for (int nt = 0; nt < 4; nt++) b[nt] = *(const short8*)Brow[nt];

    for (int k0 = 0; k0 < K; k0 += 32) {
        int kn = (k0 + 32 < K) ? (k0 + 32) : 0;
        short8 an = *(const short8*)(Arow + kn);
        short8 bn[4];
#pragma unroll
        for (int nt = 0; nt < 4; nt++) bn[nt] = *(const short8*)(Brow[nt] + kn);
#pragma unroll
        for (int nt = 0; nt < 4; nt++)
            acc[nt] = __builtin_amdgcn_mfma_f32_16x16x32_bf16(a, b[nt], acc[nt], 0, 0, 0);
        a = an;
#pragma unroll
        for (int nt = 0; nt < 4; nt++) b[nt] = bn[nt];
    }

    // GEMM wave w covers batch rows w*16..w*16+15 => bt == w
#pragma unroll
    for (int nt = 0; nt < 4; nt++) {
        int col = n0 + nt * 16 + r16;
        float bias = bi[col] + (col < 2 * H_ ? bh[col] : 0.f);
        us4 pk;
#pragma unroll
        for (int j = 0; j < 4; j++) pk[j] = f2bf(acc[nt][j] + bias);
        int gate = col >> 8, c = col & 255;
        int wv = c >> 4, r = c & 15;
        long idx = ((((long)t * 4 + w) * 16 + wv) * 3 + gate) * 256 + r * 16 + q * 4;
        *(us4*)(gid + idx) = pk;
    }
}

// Batch-split scan: 8 WGs (dir = bx>>2, btile = bx&3), 1024 thr = 16 waves.
// Wave wv owns h-cols [wv*16, wv*16+16) for ALL 3 gates -> bfrag = 96 VGPRs.
// amdgpu_waves_per_eu(4,4) pins the 128-VGPR tier; scalarized global offsets
// (readfirstlane) keep peak demand ~126 <= 128 so bfrag stays resident.
template<int IS_LAST>
__global__ __attribute__((amdgpu_flat_work_group_size(1024, 1024), amdgpu_waves_per_eu(4, 4)))
void k_scan(const ushort* __restrict__ gi,
            const ushort* __restrict__ Ehh,  // [2][768][256] bf16 (this layer)
            const float* __restrict__ bhh,   // [2][768]
            const float* __restrict__ h0,    // [2][64][256] f32 (this layer)
            ushort* __restrict__ out_bf,     // Xbuf [M][512] (layers 0..4)
            float* __restrict__ out_f) {     // d_out [M][512] (layer 5)
    int bx = blockIdx.x;
    int dir = bx >> 2, bt = bx & 3, b0 = bt * 16;
    int tid = threadIdx.x, lane = tid & 63;
    int wv = __builtin_amdgcn_readfirstlane(tid >> 6);   // wave-uniform -> SGPR math
    int r16 = lane & 15, q = lane >> 4;
    int js = wv * 16;

    const ushort* gid = gi + (long)dir * T_ * G_ * B_;
    const ushort* Ed  = Ehh + (long)dir * G_ * H_;
    const float*  bhd = bhh + dir * G_;
    const float*  h0d = h0 + (long)dir * B_ * H_;

    __shared__ ushort hl[2][16 * 256];   // 16 KiB, XOR-swizzled 512B rows

    // Whh fragments: 3 gates x 8 k-steps for this wave's 16 cols = 96 VGPRs
    short8 bfrag[3][8];
#pragma unroll
    for (int nt = 0; nt < 3; nt++) {
        int g = nt * H_ + js + r16;
#pragma unroll
        for (int ks = 0; ks < 8; ks++)
            bfrag[nt][ks] = *(const short8*)(Ed + (long)g * H_ + ks * 32 + q * 8);
    }
    float bhn = bhd[2 * H_ + js + r16];

    // init LDS h[0] (swizzled): wave wv loads batch row wv; lane covers 4 cols
    {
        int row = wv, c0 = lane * 4;
        const float* src = h0d + (long)(b0 + row) * H_ + c0;
        us4 pk;
#pragma unroll
        for (int i = 0; i < 4; i++) pk[i] = f2bf(src[i]);
        char* dst = (char*)&hl[0][0] + row * 512 + ((c0 * 2) ^ ((row & 7) << 4));
        *(us4*)dst = pk;
    }
    // h_old carried per-lane as packed bf16 (rows q*4+j, col js+r16)
    us4 hprev;
#pragma unroll
    for (int j = 0; j < 4; j++)
        hprev[j] = f2bf(h0d[(long)(b0 + q * 4 + j) * H_ + js + r16]);
    wg_barrier();

    int t0 = dir ? (T_ - 1) : 0;
    // scalar (wave-uniform) evolving offsets; per-lane parts are small ints
    long gstep = dir ? -(long)(4 * 16 * 3 * 256) : (long)(4 * 16 * 3 * 256);
    long gi_off = ((((long)t0 * 4 + bt) * 16 + wv) * 3) * 256;
    int  gi_ln  = r16 * 16 + q * 4;

    long xstep = dir ? -(long)B_ * 512 : (long)B_ * 512;
    long x_off = ((long)t0 * B_ + b0 + wv) * 512 + dir * H_;
    int  x_ln  = lane * 4;
    int bnc_off = wv * 512 + ((lane * 8) ^ ((wv & 7) << 4));

    int sw = (r16 & 7) << 4;
    for (int s = 0; s < T_; s++) {
        const char* hc = (const char*)&hl[s & 1][0];
        char* hn_ = (char*)&hl[(s & 1) ^ 1][0];

        // gi loads for this step (3 x 8B, one scalar base + imm offsets), issued early
        us4 gv0 = *(const us4*)(gid + gi_off + gi_ln);
        us4 gv1 = *(const us4*)(gid + gi_off + gi_ln + 256);
        us4 gv2 = *(const us4*)(gid + gi_off + gi_ln + 512);
        gi_off += gstep;

        // bounce previous step's h (in hc) to global, coalesced
        if (s) {
            us4 v = *(const us4*)(hc + bnc_off);
            if (IS_LAST) {
                f32x4 f0;
#pragma unroll
                for (int i = 0; i < 4; i++) f0[i] = bf2f(v[i]);
                *(f32x4*)(out_f + x_off + x_ln) = f0;
            } else {
                *(us4*)(out_bf + x_off + x_ln) = v;
            }
            x_off += xstep;
        }

        // gh = h @ Whh^T for this wave's 16 cols, 3 gates
        f32x4 acc0 = {0.f, 0.f, 0.f, 0.f};
        f32x4 acc1 = {0.f, 0.f, 0.f, 0.f};
        f32x4 acc2 = {bhn, bhn, bhn, bhn};
#pragma unroll
        for (int ks = 0; ks < 8; ks++) {
            short8 a = *(const short8*)(hc + r16 * 512 + ((ks * 64 + q * 16) ^ sw));
            acc0 = __builtin_amdgcn_mfma_f32_16x16x32_bf16(a, bfrag[0][ks], acc0, 0, 0, 0);
            acc1 = __builtin_amdgcn_mfma_f32_16x16x32_bf16(a, bfrag[1][ks], acc1, 0, 0, 0);
            acc2 = __builtin_amdgcn_mfma_f32_16x16x32_bf16(a, bfrag[2][ks], acc2, 0, 0, 0);
        }

        // gates + state update; h_new -> other LDS buffer (swizzled)
        int col = js + r16;
#pragma unroll
        for (int j = 0; j < 4; j++) {
            int row = q * 4 + j;
            float xr = acc0[j] + bf2f(gv0[j]);
            float xz = acc1[j] + bf2f(gv1[j]);
            float r = fast_rcp(1.f + __expf(-xr));
            float z = fast_rcp(1.f + __expf(-xz));
            float xn = bf2f(gv2[j]) + r * acc2[j];
            float n = 1.f - 2.f * fast_rcp(__expf(2.f * xn) + 1.f);  // tanh
            float hnew = n + z * (bf2f(hprev[j]) - n);
            ushort us = f2bf(hnew);
            hprev[j] = us;
            *(ushort*)(hn_ + row * 512 + ((col * 2) ^ ((row & 7) << 4))) = us;
        }
        wg_barrier();
    }

    // final bounce: h(T-1) sits in hl[0]
    {
        const char* hc = (const char*)&hl[0][0];
        us4 v = *(const us4*)(hc + bnc_off);
        if (IS_LAST) {
            f32x4 f0;
#pragma unroll
            for (int i = 0; i < 4; i++) f0[i] = bf2f(v[i]);
            *(f32x4*)(out_f + x_off + x_ln) = f0;
        } else {
            *(us4*)(out_bf + x_off + x_ln) = v;
        }
    }
}

extern "C" void kernel_launch(void* const* d_in, const int* in_sizes, int n_in,
                              void* d_out, int out_size, void* d_ws, size_t ws_size,
                              hipStream_t stream) {
    const float* x      = (const float*)d_in[0];
    const float* h0     = (const float*)d_in[1];
    const float* w_ih_0 = (const float*)d_in[2];
    const float* w_hh_0 = (const float*)d_in[3];
    const float* b_ih_0 = (const float*)d_in[4];
    const float* b_hh_0 = (const float*)d_in[5];
    const float* w_ih_r = (const float*)d_in[6];
    const float* w_hh_r = (const float*)d_in[7];
    const float* b_ih_r = (const float*)d_in[8];
    const float* b_hh_r = (const float*)d_in[9];
    float* out = (float*)d_out;

    char* ws = (char*)d_ws;
    size_t off = 0;
    auto alloc = [&](size_t bytes) -> void* {
        void* p = ws + off;
        off = (off + bytes + 255) & ~(size_t)255;
        return p;
    };
    ushort* Ehh  = (ushort*)alloc(12L * G_ * H_ * 2);        // [6][2][768][256]
    ushort* Eih0 = (ushort*)alloc(2L * G_ * I_ * 2);         // [2][768][128]
    ushort* EihR = (ushort*)alloc(10L * G_ * 512 * 2);       // [5][2][768][512]
    ushort* gi   = (ushort*)alloc(2L * T_ * G_ * B_ * 2);    // [2][512][4][16][3][256] (tiled)
    ushort* Xbuf = (ushort*)alloc((long)M_ * 512 * 2);       // [32768][512]

    k_transpose_cast<<<dim3(256, 1, 2),  256, 0, stream>>>(w_hh_0, Ehh, H_);
    k_transpose_cast<<<dim3(256, 1, 10), 256, 0, stream>>>(w_hh_r, Ehh + 2L * G_ * H_, H_);
    k_transpose_cast<<<dim3(128, 1, 2),  256, 0, stream>>>(w_ih_0, Eih0, I_);
    k_transpose_cast<<<dim3(512, 1, 10), 256, 0, stream>>>(w_ih_r, EihR, 512);
    k_cast<<<dim3(2048), 256, 0, stream>>>(x, Xbuf, (long)M_ * I_);

    for (int l = 0; l < L_; l++) {
        int K = (l == 0) ? I_ : 512;
        const ushort* Eih = (l == 0) ? Eih0 : (EihR + (long)(l - 1) * 2 * G_ * 512);
        const float* bih = (l == 0) ? b_ih_0 : (b_ih_r + (long)(l - 1) * 2 * G_);
        const float* bhh = (l == 0) ? b_hh_0 : (b_hh_r + (long)(l - 1) * 2 * G_);
        const ushort* Ehl = Ehh + (long)l * 2 * G_ * H_;
        const float* h0l = h0 + (long)l * 2 * B_ * H_;

        k_gi_gemm<<<dim3(T_, G_ / 64, 2), 256, 0, stream>>>(Xbuf, Eih, bih, bhh, gi, K);

        if (l == L_ - 1)
            k_scan<1><<<dim3(8), dim3(1024), 0, stream>>>(gi, Ehl, bhh, h0l, Xbuf, out);
        else
            k_scan<0><<<dim3(8), dim3(1024), 0, stream>>>(gi, Ehl, bhh, h0l, Xbuf, out);
    }
}

// Round 7
// 13266.759 us; speedup vs baseline: 1.1685x; 1.1626x over previous
//
#include <hip/hip_runtime.h>
#include <hip/hip_bf16.h>

#define T_ 512
#define B_ 64
#define I_ 128
#define H_ 256
#define G_ 768   // 3H
#define L_ 6
#define M_ (T_ * B_)   // 32768

typedef __attribute__((ext_vector_type(8))) short short8;
typedef __attribute__((ext_vector_type(4))) float f32x4;
typedef __attribute__((ext_vector_type(4))) unsigned short us4;

__device__ __forceinline__ ushort f2bf(float x) {
    union { float f; unsigned u; } v; v.f = x;
    unsigned r = v.u + 0x7FFFu + ((v.u >> 16) & 1u);
    return (ushort)(r >> 16);
}
__device__ __forceinline__ float bf2f(ushort h) {
    union { unsigned u; float f; } v; v.u = ((unsigned)h) << 16;
    return v.f;
}
__device__ __forceinline__ float fast_rcp(float x) {
#if __has_builtin(__builtin_amdgcn_rcpf)
    return __builtin_amdgcn_rcpf(x);
#else
    return 1.0f / x;
#endif
}
// barrier without vmcnt(0) drain: LDS-visible only; global stores float across steps
__device__ __forceinline__ void wg_barrier() {
    asm volatile("s_waitcnt lgkmcnt(0)" ::: "memory");
    __builtin_amdgcn_s_barrier();
    asm volatile("" ::: "memory");
}

// dst[m][k] = bf16( src[m][ (k%768)*cols + k/768 ] ) -- the _eff reinterpretation
__global__ void k_transpose_cast(const float* __restrict__ src, ushort* __restrict__ dst,
                                 int cols) {
    long per = 768L * cols;
    long m = blockIdx.z;
    for (long k = (long)blockIdx.x * blockDim.x + threadIdx.x; k < per;
         k += (long)gridDim.x * blockDim.x) {
        long r = k % 768, c = k / 768;
        dst[m * per + k] = f2bf(src[m * per + r * cols + c]);
    }
}

__global__ void k_cast(const float* __restrict__ src, ushort* __restrict__ dst, long n) {
    long i = (long)blockIdx.x * blockDim.x + threadIdx.x;
    long stride = (long)gridDim.x * blockDim.x;
    for (; i < n; i += stride) dst[i] = f2bf(src[i]);
}

// gi layout per dir: [t][bt(4)][ws(8)][nt*2+ct(6)][r16(16)][b(16)] bf16
// (matches the 8-wave scan: wave ws owns cols [ws*32, ws*32+32), bt = batch tile)
__global__ __launch_bounds__(256)
void k_gi_gemm(const ushort* __restrict__ A,    // [M][K] bf16
               const ushort* __restrict__ E,    // [2][768][K] bf16
               const float* __restrict__ bih,   // [2][768]
               const float* __restrict__ bhh,   // [2][768]
               ushort* __restrict__ gi,
               int K) {
    int dir = blockIdx.z;
    const ushort* Bd = E + (long)dir * G_ * K;
    const float* bi = bih + dir * G_;
    const float* bh = bhh + dir * G_;
    ushort* gid = gi + (long)dir * T_ * G_ * B_;

    int t = blockIdx.x;
    int n0 = blockIdx.y * 64;
    int lane = threadIdx.x & 63, w = threadIdx.x >> 6;
    int r16 = lane & 15, q = lane >> 4, koff = q * 8;

    const ushort* Arow = A + (long)(t * 64 + w * 16 + r16) * K + koff;
    const ushort* Brow[4];
#pragma unroll
    for (int nt = 0; nt < 4; nt++)
        Brow[nt] = Bd + (long)(n0 + nt * 16 + r16) * K + koff;

    f32x4 acc[4] = {{0.f,0.f,0.f,0.f},{0.f,0.f,0.f,0.f},{0.f,0.f,0.f,0.f},{0.f,0.f,0.f,0.f}};

    short8 a = *(const short8*)Arow;
    short8 b[4];
#pragma unroll
    for (int nt = 0; nt < 4; nt++) b[nt] = *(const short8*)Brow[nt];

    for (int k0 = 0; k0 < K; k0 += 32) {
        int kn = (k0 + 32 < K) ? (k0 + 32) : 0;
        short8 an = *(const short8*)(Arow + kn);
        short8 bn[4];
#pragma unroll
        for (int nt = 0; nt < 4; nt++) bn[nt] = *(const short8*)(Brow[nt] + kn);
#pragma unroll
        for (int nt = 0; nt < 4; nt++)
            acc[nt] = __builtin_amdgcn_mfma_f32_16x16x32_bf16(a, b[nt], acc[nt], 0, 0, 0);
        a = an;
#pragma unroll
        for (int nt = 0; nt < 4; nt++) b[nt] = bn[nt];
    }

    // GEMM wave w covers batch rows w*16..w*16+15 => bt == w
#pragma unroll
    for (int nt = 0; nt < 4; nt++) {
        int col = n0 + nt * 16 + r16;
        float bias = bi[col] + (col < 2 * H_ ? bh[col] : 0.f);
        us4 pk;
#pragma unroll
        for (int j = 0; j < 4; j++) pk[j] = f2bf(acc[nt][j] + bias);
        int gate = col >> 8, c = col & 255;
        int ws = c >> 5, ct = (c >> 4) & 1, r = c & 15;
        long idx = ((((long)t * 4 + w) * 8 + ws) * 6 + gate * 2 + ct) * 256 + r * 16 + q * 4;
        *(us4*)(gid + idx) = pk;
    }
}

// Batch-split scan: 8 WGs (dir = bx>>2, btile = bx&3), 512 thr = 8 waves,
// 2 waves/SIMD (amdgpu_waves_per_eu(2,2) -> 256-reg budget). Whh fragments
// (192 regs/wave) are PINNED via empty asm volatile so LLVM cannot
// rematerialize the loads inside the 512-step loop (the R2-R6 failure mode).
template<int IS_LAST>
__global__ __attribute__((amdgpu_flat_work_group_size(512, 512), amdgpu_waves_per_eu(2, 2)))
void k_scan(const ushort* __restrict__ gi,
            const ushort* __restrict__ Ehh,  // [2][768][256] bf16 (this layer)
            const float* __restrict__ bhh,   // [2][768]
            const float* __restrict__ h0,    // [2][64][256] f32 (this layer)
            ushort* __restrict__ out_bf,     // Xbuf [M][512] (layers 0..4)
            float* __restrict__ out_f) {     // d_out [M][512] (layer 5)
    int bx = blockIdx.x;
    int dir = bx >> 2, bt = bx & 3, b0 = bt * 16;
    int tid = threadIdx.x, lane = tid & 63;
    int w = __builtin_amdgcn_readfirstlane(tid >> 6);  // wave id, wave-uniform
    int r16 = lane & 15, q = lane >> 4;
    int js = w * 32;

    const ushort* gid = gi + (long)dir * T_ * G_ * B_;
    const ushort* Ed  = Ehh + (long)dir * G_ * H_;
    const float*  bhd = bhh + dir * G_;
    const float*  h0d = h0 + (long)dir * B_ * H_;

    __shared__ ushort hl[2][16 * 256];   // 16 KiB, XOR-swizzled 512B rows

    // Whh fragments: 3 gates x 2 col-tiles x 8 k-steps = 192 VGPRs, pinned.
    short8 bfrag[3][2][8];
#pragma unroll
    for (int nt = 0; nt < 3; nt++)
#pragma unroll
        for (int ct = 0; ct < 2; ct++) {
            int g = nt * H_ + js + ct * 16 + r16;
#pragma unroll
            for (int ks = 0; ks < 8; ks++)
                bfrag[nt][ct][ks] = *(const short8*)(Ed + (long)g * H_ + ks * 32 + q * 8);
        }
#pragma unroll
    for (int nt = 0; nt < 3; nt++)
#pragma unroll
        for (int ct = 0; ct < 2; ct++)
#pragma unroll
            for (int ks = 0; ks < 8; ks++)
                asm volatile("" : "+v"(bfrag[nt][ct][ks]));   // non-rematerializable now

    float bhn[2];
#pragma unroll
    for (int ct = 0; ct < 2; ct++) bhn[ct] = bhd[2 * H_ + js + ct * 16 + r16];
#pragma unroll
    for (int ct = 0; ct < 2; ct++) asm volatile("" : "+v"(bhn[ct]));

    // init LDS h[0] (swizzled) from h0
    {
        int row = tid >> 5, c0 = (tid & 31) * 8;
        const float* src = h0d + (long)(b0 + row) * H_ + c0;
        union { ushort u[8]; short8 v; } pk;
#pragma unroll
        for (int i = 0; i < 8; i++) pk.u[i] = f2bf(src[i]);
        char* dst = (char*)&hl[0][0] + row * 512 + ((c0 * 2) ^ ((row & 7) << 4));
        *(short8*)dst = pk.v;
    }
    // h_old carried per-lane as packed bf16 (rows q*4+j, cols js+ct*16+r16)
    us4 hprev[2];
#pragma unroll
    for (int ct = 0; ct < 2; ct++) {
        us4 tmp;
#pragma unroll
        for (int j = 0; j < 4; j++)
            tmp[j] = f2bf(h0d[(long)(b0 + q * 4 + j) * H_ + js + ct * 16 + r16]);
        hprev[ct] = tmp;
    }
    wg_barrier();

    int t0 = dir ? (T_ - 1) : 0;
    // evolving offsets: wave-uniform long (SGPR) + small per-lane int
    long gstep = dir ? -(long)(4 * 8 * 6 * 256) : (long)(4 * 8 * 6 * 256);
    long gi_off = (((long)t0 * 4 + bt) * 8 + w) * 6 * 256;
    int  gi_ln  = r16 * 16 + q * 4;

    long xstep = dir ? -(long)B_ * 512 : (long)B_ * 512;
    long x_off = ((long)t0 * B_ + b0) * 512 + dir * H_;
    int brow = tid >> 5, i16 = tid & 31;
    int x_ln = brow * 512 + i16 * 8;
    int bnc_off = brow * 512 + ((i16 * 16) ^ ((brow & 7) << 4));

    int sw = (r16 & 7) << 4;
    for (int s = 0; s < T_; s++) {
        const char* hc = (const char*)&hl[s & 1][0];
        char* hn_ = (char*)&hl[(s & 1) ^ 1][0];

        // gi loads for this step (6 x 8B, scalar base + imm offsets), issued early
        us4 gv[3][2];
#pragma unroll
        for (int nt = 0; nt < 3; nt++)
#pragma unroll
            for (int ct = 0; ct < 2; ct++)
                gv[nt][ct] = *(const us4*)(gid + gi_off + gi_ln + (nt * 2 + ct) * 256);
        gi_off += gstep;

        // bounce previous step's h (in hc) to global, coalesced 16B/thread
        if (s) {
            short8 v = *(const short8*)(hc + bnc_off);
            if (IS_LAST) {
                union { short8 v; ushort u[8]; } pk; pk.v = v;
                f32x4 f0, f1;
#pragma unroll
                for (int i = 0; i < 4; i++) { f0[i] = bf2f(pk.u[i]); f1[i] = bf2f(pk.u[4 + i]); }
                *(f32x4*)(out_f + x_off + x_ln) = f0;
                *(f32x4*)(out_f + x_off + x_ln + 4) = f1;
            } else {
                *(short8*)(out_bf + x_off + x_ln) = v;
            }
            x_off += xstep;
        }

        // gh = h @ Whh^T ; n-gate bias preloaded into accumulator
        f32x4 acc[3][2];
#pragma unroll
        for (int ct = 0; ct < 2; ct++) {
            acc[0][ct] = (f32x4){0.f, 0.f, 0.f, 0.f};
            acc[1][ct] = (f32x4){0.f, 0.f, 0.f, 0.f};
            acc[2][ct] = (f32x4){bhn[ct], bhn[ct], bhn[ct], bhn[ct]};
        }
#pragma unroll
        for (int ks = 0; ks < 8; ks++) {
            short8 a = *(const short8*)(hc + r16 * 512 + ((ks * 64 + q * 16) ^ sw));
#pragma unroll
            for (int nt = 0; nt < 3; nt++)
#pragma unroll
                for (int ct = 0; ct < 2; ct++)
                    acc[nt][ct] = __builtin_amdgcn_mfma_f32_16x16x32_bf16(a, bfrag[nt][ct][ks], acc[nt][ct], 0, 0, 0);
        }

        // gates + state update; h_new -> other LDS buffer (swizzled)
#pragma unroll
        for (int ct = 0; ct < 2; ct++) {
            int col = js + ct * 16 + r16;
#pragma unroll
            for (int j = 0; j < 4; j++) {
                int row = q * 4 + j;
                float xr = acc[0][ct][j] + bf2f(gv[0][ct][j]);
                float xz = acc[1][ct][j] + bf2f(gv[1][ct][j]);
                float r = fast_rcp(1.f + __expf(-xr));
                float z = fast_rcp(1.f + __expf(-xz));
                float xn = bf2f(gv[2][ct][j]) + r * acc[2][ct][j];
                float n = 1.f - 2.f * fast_rcp(__expf(2.f * xn) + 1.f);  // tanh
                float hnew = n + z * (bf2f(hprev[ct][j]) - n);
                ushort us = f2bf(hnew);
                hprev[ct][j] = us;
                *(ushort*)(hn_ + row * 512 + ((col * 2) ^ ((row & 7) << 4))) = us;
            }
        }
        wg_barrier();
    }

    // final bounce: h(T-1) sits in hl[0]
    {
        const char* hc = (const char*)&hl[0][0];
        short8 v = *(const short8*)(hc + bnc_off);
        if (IS_LAST) {
            union { short8 v; ushort u[8]; } pk; pk.v = v;
            f32x4 f0, f1;
#pragma unroll
            for (int i = 0; i < 4; i++) { f0[i] = bf2f(pk.u[i]); f1[i] = bf2f(pk.u[4 + i]); }
            *(f32x4*)(out_f + x_off + x_ln) = f0;
            *(f32x4*)(out_f + x_off + x_ln + 4) = f1;
        } else {
            *(short8*)(out_bf + x_off + x_ln) = v;
        }
    }
}

extern "C" void kernel_launch(void* const* d_in, const int* in_sizes, int n_in,
                              void* d_out, int out_size, void* d_ws, size_t ws_size,
                              hipStream_t stream) {
    const float* x      = (const float*)d_in[0];
    const float* h0     = (const float*)d_in[1];
    const float* w_ih_0 = (const float*)d_in[2];
    const float* w_hh_0 = (const float*)d_in[3];
    const float* b_ih_0 = (const float*)d_in[4];
    const float* b_hh_0 = (const float*)d_in[5];
    const float* w_ih_r = (const float*)d_in[6];
    const float* w_hh_r = (const float*)d_in[7];
    const float* b_ih_r = (const float*)d_in[8];
    const float* b_hh_r = (const float*)d_in[9];
    float* out = (float*)d_out;

    char* ws = (char*)d_ws;
    size_t off = 0;
    auto alloc = [&](size_t bytes) -> void* {
        void* p = ws + off;
        off = (off + bytes + 255) & ~(size_t)255;
        return p;
    };
    ushort* Ehh  = (ushort*)alloc(12L * G_ * H_ * 2);        // [6][2][768][256]
    ushort* Eih0 = (ushort*)alloc(2L * G_ * I_ * 2);         // [2][768][128]
    ushort* EihR = (ushort*)alloc(10L * G_ * 512 * 2);       // [5][2][768][512]
    ushort* gi   = (ushort*)alloc(2L * T_ * G_ * B_ * 2);    // [2][512][4][8][6][256] (tiled)
    ushort* Xbuf = (ushort*)alloc((long)M_ * 512 * 2);       // [32768][512]

    k_transpose_cast<<<dim3(256, 1, 2),  256, 0, stream>>>(w_hh_0, Ehh, H_);
    k_transpose_cast<<<dim3(256, 1, 10), 256, 0, stream>>>(w_hh_r, Ehh + 2L * G_ * H_, H_);
    k_transpose_cast<<<dim3(128, 1, 2),  256, 0, stream>>>(w_ih_0, Eih0, I_);
    k_transpose_cast<<<dim3(512, 1, 10), 256, 0, stream>>>(w_ih_r, EihR, 512);
    k_cast<<<dim3(2048), 256, 0, stream>>>(x, Xbuf, (long)M_ * I_);

    for (int l = 0; l < L_; l++) {
        int K = (l == 0) ? I_ : 512;
        const ushort* Eih = (l == 0) ? Eih0 : (EihR + (long)(l - 1) * 2 * G_ * 512);
        const float* bih = (l == 0) ? b_ih_0 : (b_ih_r + (long)(l - 1) * 2 * G_);
        const float* bhh = (l == 0) ? b_hh_0 : (b_hh_r + (long)(l - 1) * 2 * G_);
        const ushort* Ehl = Ehh + (long)l * 2 * G_ * H_;
        const float* h0l = h0 + (long)l * 2 * B_ * H_;

        k_gi_gemm<<<dim3(T_, G_ / 64, 2), 256, 0, stream>>>(Xbuf, Eih, bih, bhh, gi, K);

        if (l == L_ - 1)
            k_scan<1><<<dim3(8), dim3(512), 0, stream>>>(gi, Ehl, bhh, h0l, Xbuf, out);
        else
            k_scan<0><<<dim3(8), dim3(512), 0, stream>>>(gi, Ehl, bhh, h0l, Xbuf, out);
    }
}